// Round 7
// baseline (458.753 us; speedup 1.0000x reference)
//
#include <hip/hip_runtime.h>
#include <math.h>
#include <stdint.h>

// Problem constants
constexpr int BB  = 16;
constexpr int CH  = 96;            // CIN == COUT == 96
constexpr int HH  = 96;
constexpr int WW  = 96;
constexpr int HWI = HH * WW;       // 9216
constexpr int CHW = CH * HWI;      // 884736
constexpr int IMG = BB * CHW;      // elems per [B,C,H,W] tensor
constexpr int ATT = BB * CH * CH * 9;  // 1327104 floats
constexpr int WPK = 27 * 6 * 64 * 8;   // 82944 bf16 elems per packed weight matrix

typedef short short8 __attribute__((ext_vector_type(8)));
typedef float floatx4 __attribute__((ext_vector_type(4)));

__device__ __forceinline__ ushort f2bf(float f) {
  union { float f; unsigned u; } v; v.f = f;
  unsigned r = (v.u + 0x7fffu + ((v.u >> 16) & 1u)) >> 16;  // RNE
  return (ushort)r;
}
__device__ __forceinline__ float bf2f(ushort h) {
  union { float f; unsigned u; } v; v.u = ((unsigned)h) << 16;
  return v.f;
}
// hi/lo error-split pack: hi = bf16(v), lo = bf16(v - hi), word = hi | lo<<16
__device__ __forceinline__ uint packhl(float v) {
  const ushort h = f2bf(v);
  const ushort l = f2bf(v - bf2f(h));
  return (uint)h | ((uint)l << 16);
}

// ---------------------------------------------------------------------------
// X cast/transpose: fp32 NCHW -> bf16 NHWC, done ONCE (unchanged).
// ---------------------------------------------------------------------------
__global__ __launch_bounds__(256) void xcast(
    const float* __restrict__ X, ushort* __restrict__ Xn)
{
  const int b  = blockIdx.y;
  const int p0 = blockIdx.x * 256;
  const int tid = threadIdx.x;
  __shared__ ushort T[256 * 104];

  const float* xb = X + (size_t)b * CHW + p0;
#pragma unroll 8
  for (int c = 0; c < 96; c += 2) {
    const ushort h0 = f2bf(xb[(size_t)c * HWI + tid]);
    const ushort h1 = f2bf(xb[(size_t)(c + 1) * HWI + tid]);
    *(uint*)(&T[tid * 104 + c]) = (uint)h0 | ((uint)h1 << 16);
  }
  __syncthreads();

  ushort* ob = Xn + (size_t)b * CHW + (size_t)p0 * 96;
#pragma unroll
  for (int it = 0; it < 12; ++it) {
    const int idx = it * 256 + tid;                 // < 3072
    const int pix = (idx * 2731) >> 15;             // idx / 12
    const int c8  = idx - pix * 12;
    *(short8*)(ob + pix * 96 + c8 * 8) = *(const short8*)(&T[pix * 104 + c8 * 8]);
  }
}

// ---------------------------------------------------------------------------
// Weight prepack (unchanged).
// ---------------------------------------------------------------------------
__global__ __launch_bounds__(256) void prepack(
    const float* __restrict__ src, ushort* __restrict__ dst)
{
  const int g = blockIdx.y;
  const int p = blockIdx.x * 256 + threadIdx.x;   // 0..82943
  const float* s = src + (size_t)g * WPK;
  ushort* d = dst + (size_t)g * WPK;
  const int j    = p & 7;
  const int lane = (p >> 3) & 63;
  const int rest = p >> 9;                        // 0..161
  const int mt = rest % 6;
  const int kc = rest / 6;
  const int m  = mt * 16 + (lane & 15);
  const int k  = kc * 32 + (lane >> 4) * 8 + j;
  const int ci = k % 96;
  const int o  = k / 96;
  d[p] = f2bf(s[m * 864 + ci * 9 + o]);
}

// ---------------------------------------------------------------------------
// Implicit-GEMM 3x3 conv, round 7: WEIGHTS IN REGISTERS (streamed from L2
// with next-chunk prefetch), LDS holds ONLY the X tile (52 KB) -> 2
// blocks/CU. K-loop has ZERO barriers (single sync after X staging).
// 512 thr = 8 waves: wave = (row-group wr = w8>>1, mt-half = w8&1);
// per wave 243 MFMA, acc 3x3 (36 VGPR), af/afn prefetch 24 VGPR.
// OUTM: 0 = packed hi/lo uint CLASS-MAJOR [b][k][c][1024], 1 = bf16 NHWC,
//       2 = fp32 NCHW.
// ---------------------------------------------------------------------------
template<int OUTM>
__global__ __launch_bounds__(512, 4) void conv_nb(
    const ushort* __restrict__ Xn,   // [B][H][W][C] bf16
    const ushort* __restrict__ Wpk,  // packed weights
    void* __restrict__ Yv, int wbstride)
{
  const int b    = blockIdx.y;
  const int tile = blockIdx.x;
  const int ty0  = (tile / 6) * 12;
  const int tx0  = (tile % 6) * 16;
  const int tid  = threadIdx.x;
  const int lane = tid & 63;
  const int w8   = tid >> 6;         // 0..7
  const int wr   = w8 >> 1;          // row group 0..3
  const int half = w8 & 1;           // mt half
  const int nc   = lane & 15;
  const int q    = lane >> 4;

  __shared__ __attribute__((aligned(16))) ushort Xs[252 * 104];  // 52416 B

  // per-wave weight stream base: this wave's 3 mt fragments per chunk
  const ushort* wph = Wpk + (size_t)b * wbstride + (size_t)(half * 3) * 512
                    + lane * 8;

  // ---- stage X tile: 252 pixels x 96 ch from NHWC bf16, coalesced 16B
  const ushort* xb = Xn + (size_t)b * CHW;
  for (int it = 0; it < 6; ++it) {
    const int idx = it * 512 + tid;
    if (idx < 3024) {
      const int pix = (idx * 2731) >> 15;          // idx / 12
      const int c8  = idx - pix * 12;
      const int ly  = (pix * 57) >> 10;            // pix / 18
      const int lx  = pix - ly * 18;
      const int gy  = ty0 - 1 + ly, gx = tx0 - 1 + lx;
      short8 v = {0, 0, 0, 0, 0, 0, 0, 0};
      if (((unsigned)gy < 96u) & ((unsigned)gx < 96u))
        v = *(const short8*)(xb + ((size_t)gy * WW + gx) * 96 + c8 * 8);
      *(short8*)(&Xs[pix * 104 + c8 * 8]) = v;
    }
  }

  // preload chunk-0 weights while staging drains
  short8 af[3];
#pragma unroll
  for (int m = 0; m < 3; ++m)
    af[m] = *(const short8*)(wph + m * 512);

  floatx4 acc[3][3];
#pragma unroll
  for (int mtl = 0; mtl < 3; ++mtl)
#pragma unroll
    for (int t = 0; t < 3; ++t)
#pragma unroll
      for (int r = 0; r < 4; ++r) acc[mtl][t][r] = 0.f;

  __syncthreads();   // X tile resident; ONLY barrier in the kernel

#pragma unroll
  for (int ch = 0; ch < 27; ++ch) {
    // prefetch next chunk's weights (no barrier anywhere to stall them)
    short8 afn[3];
    if (ch < 26) {
#pragma unroll
      for (int m = 0; m < 3; ++m)
        afn[m] = *(const short8*)(wph + (size_t)(ch + 1) * 3072 + m * 512);
    }

    const int o  = ch / 3;
    const int cc = ch - o * 3;
    const int dy = o / 3, dx = o - dy * 3;
    const int pc  = nc + dx;
    const int cib = cc * 32 + q * 8;

    short8 bfr[3];
#pragma unroll
    for (int t = 0; t < 3; ++t) {
      const int pix = (3 * wr + t + dy) * 18 + pc;
      bfr[t] = *(const short8*)(&Xs[pix * 104 + cib]);
    }

#pragma unroll
    for (int mtl = 0; mtl < 3; ++mtl)
#pragma unroll
      for (int t = 0; t < 3; ++t)
        acc[mtl][t] = __builtin_amdgcn_mfma_f32_16x16x32_bf16(
            af[mtl], bfr[t], acc[mtl][t], 0, 0, 0);

#pragma unroll
    for (int m = 0; m < 3; ++m) af[m] = afn[m];
  }

  // ---- epilogue
#pragma unroll
  for (int mtl = 0; mtl < 3; ++mtl)
#pragma unroll
    for (int t = 0; t < 3; ++t) {
      const int yy = ty0 + 3 * wr + t;
      const int xx = tx0 + nc;
#pragma unroll
      for (int r = 0; r < 4; ++r) {
        const int co = (half * 3 + mtl) * 16 + q * 4 + r;
        if constexpr (OUTM == 0) {
          // class-major: ty0 % 3 == 0 so kh = t, class-row = ty0/3 + wr
          const int cx = xx / 3;
          const int kw = xx - 3 * cx;
          const int kk = t * 3 + kw;
          const int cp = (ty0 / 3 + wr) * 32 + cx;
          ((uint*)Yv)[(((size_t)b * 9 + kk) * CH + co) * 1024 + cp] =
              packhl(acc[mtl][t][r]);
        } else if constexpr (OUTM == 1) {
          ((ushort*)Yv + (size_t)b * CHW)[((size_t)yy * WW + xx) * 96 + co] =
              f2bf(acc[mtl][t][r]);
        } else {
          ((float*)Yv + (size_t)b * CHW)[(size_t)co * HWI + yy * WW + xx] =
              acc[mtl][t][r];
        }
      }
    }
}

// ---------------------------------------------------------------------------
// Attention Gram GEMM, K-split x4 (unchanged). Y1/Y2 arrive CLASS-MAJOR
// [b][k][c][1024] hi/lo-packed -> coalesced uint4 staging.
// ---------------------------------------------------------------------------
__global__ __launch_bounds__(256) void attn_mfma(
    const uint* __restrict__ Y1, const uint* __restrict__ Y2,
    float* __restrict__ P0, float* __restrict__ P1,
    float* __restrict__ P2, float* __restrict__ P3)
{
  const int bi = blockIdx.x;
  const int b  = bi / 36;
  const int r9 = bi % 36;
  const int k  = r9 >> 2;
  const int qd = r9 & 3;
  const int tid  = threadIdx.x;
  const int lane = tid & 63;
  const int wv   = tid >> 6;          // 0..3

  __shared__ ushort Ah[96 * 72], Al[96 * 72], Bh[96 * 72], Bl[96 * 72];

  const uint* y1b = Y1 + ((size_t)(b * 9 + k) * CH) * 1024;
  const uint* y2b = Y2 + ((size_t)(b * 9 + k) * CH) * 1024;

  const int mg2 = wv >> 1;            // c half
  const int ng2 = wv & 1;             // d half
  const int cn = lane & 15;
  const int q  = lane >> 4;

  floatx4 acc[3][3];
#pragma unroll
  for (int i = 0; i < 3; ++i)
#pragma unroll
    for (int j = 0; j < 3; ++j)
#pragma unroll
      for (int r = 0; r < 4; ++r) acc[i][j][r] = 0.f;

  const int sj4  = tid & 15;          // pixel quad within slab (4 px each)
  const int sg16 = tid >> 4;          // 0..15: row group

  for (int ss = 0; ss < 4; ++ss) {
    const int s = qd * 4 + ss;        // slab: class pixels 64s..64s+63
    __syncthreads();
#pragma unroll
    for (int cg = 0; cg < 6; ++cg) {
      const int c = cg * 16 + sg16;
      const size_t goff = (size_t)c * 1024 + s * 64 + sj4 * 4;
      const uint4 u1 = *(const uint4*)(y1b + goff);
      const uint4 u2 = *(const uint4*)(y2b + goff);
      const int lbase = c * 72 + sj4 * 4;           // 8B-aligned (144c+8sj4)
      uint2 w;
      // A hi
      w.x = (u1.x & 0xffffu) | (u1.y << 16);
      w.y = (u1.z & 0xffffu) | (u1.w << 16);
      *(uint2*)(&Ah[lbase]) = w;
      // A lo
      w.x = (u1.x >> 16) | (u1.y & 0xffff0000u);
      w.y = (u1.z >> 16) | (u1.w & 0xffff0000u);
      *(uint2*)(&Al[lbase]) = w;
      // B hi
      w.x = (u2.x & 0xffffu) | (u2.y << 16);
      w.y = (u2.z & 0xffffu) | (u2.w << 16);
      *(uint2*)(&Bh[lbase]) = w;
      // B lo
      w.x = (u2.x >> 16) | (u2.y & 0xffff0000u);
      w.y = (u2.z >> 16) | (u2.w & 0xffff0000u);
      *(uint2*)(&Bl[lbase]) = w;
    }
    __syncthreads();

#pragma unroll
    for (int kc = 0; kc < 2; ++kc) {
      short8 ah[3], al[3], bh[3], bl[3];
#pragma unroll
      for (int t = 0; t < 3; ++t) {
        const int offA = (mg2 * 48 + t * 16 + cn) * 72 + kc * 32 + q * 8;
        ah[t] = *(const short8*)(&Ah[offA]);
        al[t] = *(const short8*)(&Al[offA]);
        const int offB = (ng2 * 48 + t * 16 + cn) * 72 + kc * 32 + q * 8;
        bh[t] = *(const short8*)(&Bh[offB]);
        bl[t] = *(const short8*)(&Bl[offB]);
      }
#pragma unroll
      for (int i = 0; i < 3; ++i)
#pragma unroll
        for (int j = 0; j < 3; ++j) {
          acc[i][j] = __builtin_amdgcn_mfma_f32_16x16x32_bf16(
              ah[i], bh[j], acc[i][j], 0, 0, 0);
          acc[i][j] = __builtin_amdgcn_mfma_f32_16x16x32_bf16(
              ah[i], bl[j], acc[i][j], 0, 0, 0);
          acc[i][j] = __builtin_amdgcn_mfma_f32_16x16x32_bf16(
              al[i], bh[j], acc[i][j], 0, 0, 0);
        }
    }
  }

  float* P = (qd == 0) ? P0 : (qd == 1) ? P1 : (qd == 2) ? P2 : P3;
#pragma unroll
  for (int i = 0; i < 3; ++i)
#pragma unroll
    for (int j = 0; j < 3; ++j)
#pragma unroll
      for (int r = 0; r < 4; ++r) {
        const int c = mg2 * 48 + i * 16 + q * 4 + r;
        const int d = ng2 * 48 + j * 16 + cn;
        P[((size_t)(b * CH + d) * CH + c) * 9 + k] = acc[i][j][r];
      }
}

// ---------------------------------------------------------------------------
// Softmax over m = c*9+k (864 values) per (b,d) row; folds 4 K-partials.
// (unchanged; dst aliases P1 safely)
// ---------------------------------------------------------------------------
__global__ __launch_bounds__(256) void softmax_k(
    const float* __restrict__ P0, const float* __restrict__ P1,
    const float* __restrict__ P2, const float* __restrict__ P3,
    float* __restrict__ attnW)
{
  const int bd = blockIdx.x;
  const size_t base = (size_t)bd * 864;
  float* dst = attnW + base;
  const float rs = 0.0340216824f;          // 1/sqrt(864)
  const int tid = threadIdx.x;

  const size_t i0 = base + tid;
  float v0 = P0[i0] + P1[i0] + P2[i0] + P3[i0];
  float v1 = P0[i0 + 256] + P1[i0 + 256] + P2[i0 + 256] + P3[i0 + 256];
  float v2 = P0[i0 + 512] + P1[i0 + 512] + P2[i0 + 512] + P3[i0 + 512];
  float v3 = (tid < 96)
      ? (P0[i0 + 768] + P1[i0 + 768] + P2[i0 + 768] + P3[i0 + 768])
      : -3.0e38f;

  float mx = fmaxf(fmaxf(v0, v1), fmaxf(v2, v3));

  __shared__ float red[256];
  red[tid] = mx;
  __syncthreads();
#pragma unroll
  for (int s = 128; s > 0; s >>= 1) {
    if (tid < s) red[tid] = fmaxf(red[tid], red[tid + s]);
    __syncthreads();
  }
  mx = red[0];
  __syncthreads();

  const float e0 = expf((v0 - mx) * rs);
  const float e1 = expf((v1 - mx) * rs);
  const float e2 = expf((v2 - mx) * rs);
  const float e3 = (tid < 96) ? expf((v3 - mx) * rs) : 0.f;

  red[tid] = e0 + e1 + e2 + e3;
  __syncthreads();
#pragma unroll
  for (int s = 128; s > 0; s >>= 1) {
    if (tid < s) red[tid] += red[tid + s];
    __syncthreads();
  }
  const float inv = 1.f / red[0];

  dst[tid]       = e0 * inv;
  dst[tid + 256] = e1 * inv;
  dst[tid + 512] = e2 * inv;
  if (tid < 96) dst[tid + 768] = e3 * inv;
}

// ---------------------------------------------------------------------------
extern "C" void kernel_launch(void* const* d_in, const int* in_sizes, int n_in,
                              void* d_out, int out_size, void* d_ws, size_t ws_size,
                              hipStream_t stream)
{
  const float* x  = (const float*)d_in[0];
  const float* W1 = (const float*)d_in[1];
  const float* W2 = (const float*)d_in[2];
  const float* W3 = (const float*)d_in[3];

  float* ws    = (float*)d_ws;
  uint*  Y1    = (uint*)ws;                 // IMG uints (hi/lo, class-major)
  uint*  Y2    = Y1 + (size_t)IMG;          // IMG uints
  float* attnT = (float*)(Y2 + (size_t)IMG);// ATT floats (partial 0)
  float* attnW = attnT + ATT;               // ATT floats (partial 1 -> weights)
  ushort* pk   = (ushort*)(attnW + ATT);
  ushort* pkW1 = pk;
  ushort* pkW2 = pk + WPK;
  ushort* pkW3 = pk + 2 * (size_t)WPK;
  ushort* pkAW = pk + 3 * (size_t)WPK;      // 16 batch matrices
  ushort* Xn   = pkAW + 16 * (size_t)WPK;   // IMG ushorts (x bf16 NHWC)
  float* Pd2   = (float*)d_out;             // partials 2,3 in dead d_out
  float* Pd3   = Pd2 + ATT;
  ushort* Y3n  = (ushort*)Y1;               // Y1 region dead after attn

  const dim3 cgrid(48, BB);                 // 8x6 spatial tiles x batch

  xcast    <<<dim3(36, BB), 256, 0, stream>>>(x, Xn);

  prepack  <<<dim3(324, 1),  256, 0, stream>>>(W1, pkW1);
  prepack  <<<dim3(324, 1),  256, 0, stream>>>(W2, pkW2);
  prepack  <<<dim3(324, 1),  256, 0, stream>>>(W3, pkW3);

  conv_nb<0><<<cgrid, 512, 0, stream>>>(Xn, pkW1, Y1, 0);
  conv_nb<0><<<cgrid, 512, 0, stream>>>(Xn, pkW2, Y2, 0);

  attn_mfma<<<BB * 9 * 4, 256, 0, stream>>>(Y1, Y2, attnT, attnW, Pd2, Pd3);
  softmax_k<<<BB * CH, 256, 0, stream>>>(attnT, attnW, Pd2, Pd3, attnW);

  prepack  <<<dim3(324, BB), 256, 0, stream>>>(attnW, pkAW);

  conv_nb<1><<<cgrid, 512, 0, stream>>>(Xn, pkW3, Y3n, 0);
  conv_nb<2><<<cgrid, 512, 0, stream>>>(Y3n, pkAW, d_out, WPK);
}

// Round 8
// 356.143 us; speedup vs baseline: 1.2881x; 1.2881x over previous
//
#include <hip/hip_runtime.h>
#include <math.h>
#include <stdint.h>

// Problem constants
constexpr int BB  = 16;
constexpr int CH  = 96;            // CIN == COUT == 96
constexpr int HH  = 96;
constexpr int WW  = 96;
constexpr int HWI = HH * WW;       // 9216
constexpr int CHW = CH * HWI;      // 884736
constexpr int IMG = BB * CHW;      // elems per [B,C,H,W] tensor
constexpr int ATT = BB * CH * CH * 9;  // 1327104 floats
constexpr int WPK = 27 * 6 * 64 * 8;   // 82944 bf16 elems per packed weight matrix

typedef short short8 __attribute__((ext_vector_type(8)));
typedef float floatx4 __attribute__((ext_vector_type(4)));

__device__ __forceinline__ ushort f2bf(float f) {
  union { float f; unsigned u; } v; v.f = f;
  unsigned r = (v.u + 0x7fffu + ((v.u >> 16) & 1u)) >> 16;  // RNE
  return (ushort)r;
}
__device__ __forceinline__ float bf2f(ushort h) {
  union { float f; unsigned u; } v; v.u = ((unsigned)h) << 16;
  return v.f;
}
// hi/lo error-split pack: hi = bf16(v), lo = bf16(v - hi), word = hi | lo<<16
__device__ __forceinline__ uint packhl(float v) {
  const ushort h = f2bf(v);
  const ushort l = f2bf(v - bf2f(h));
  return (uint)h | ((uint)l << 16);
}

// ---------------------------------------------------------------------------
// X cast/transpose: fp32 NCHW -> bf16 NHWC, done ONCE (unchanged).
// ---------------------------------------------------------------------------
__global__ __launch_bounds__(256) void xcast(
    const float* __restrict__ X, ushort* __restrict__ Xn)
{
  const int b  = blockIdx.y;
  const int p0 = blockIdx.x * 256;
  const int tid = threadIdx.x;
  __shared__ ushort T[256 * 104];

  const float* xb = X + (size_t)b * CHW + p0;
#pragma unroll 8
  for (int c = 0; c < 96; c += 2) {
    const ushort h0 = f2bf(xb[(size_t)c * HWI + tid]);
    const ushort h1 = f2bf(xb[(size_t)(c + 1) * HWI + tid]);
    *(uint*)(&T[tid * 104 + c]) = (uint)h0 | ((uint)h1 << 16);
  }
  __syncthreads();

  ushort* ob = Xn + (size_t)b * CHW + (size_t)p0 * 96;
#pragma unroll
  for (int it = 0; it < 12; ++it) {
    const int idx = it * 256 + tid;                 // < 3072
    const int pix = (idx * 2731) >> 15;             // idx / 12
    const int c8  = idx - pix * 12;
    *(short8*)(ob + pix * 96 + c8 * 8) = *(const short8*)(&T[pix * 104 + c8 * 8]);
  }
}

// ---------------------------------------------------------------------------
// Weight prepack (unchanged).
// ---------------------------------------------------------------------------
__global__ __launch_bounds__(256) void prepack(
    const float* __restrict__ src, ushort* __restrict__ dst)
{
  const int g = blockIdx.y;
  const int p = blockIdx.x * 256 + threadIdx.x;   // 0..82943
  const float* s = src + (size_t)g * WPK;
  ushort* d = dst + (size_t)g * WPK;
  const int j    = p & 7;
  const int lane = (p >> 3) & 63;
  const int rest = p >> 9;                        // 0..161
  const int mt = rest % 6;
  const int kc = rest / 6;
  const int m  = mt * 16 + (lane & 15);
  const int k  = kc * 32 + (lane >> 4) * 8 + j;
  const int ci = k % 96;
  const int o  = k / 96;
  d[p] = f2bf(s[m * 864 + ci * 9 + o]);
}

// ---------------------------------------------------------------------------
// Implicit-GEMM 3x3 conv, round 8: round-7 structure (reg weights streamed
// from L2 with next-chunk prefetch, LDS = X tile only, single barrier) with
// the REGISTER BUDGET FIXED: __launch_bounds__(512,2) (the bound that gave
// 104 VGPR in round 6; the (512,4) bound forced a 64-reg squeeze -> 81 MB
// of scratch spill traffic, the round-7 regression) and NO full unroll of
// the 27-chunk loop (keeps live-range window small).
// OUTM: 0 = packed hi/lo uint CLASS-MAJOR [b][k][c][1024], 1 = bf16 NHWC,
//       2 = fp32 NCHW.
// ---------------------------------------------------------------------------
template<int OUTM>
__global__ __launch_bounds__(512, 2) void conv_nb(
    const ushort* __restrict__ Xn,   // [B][H][W][C] bf16
    const ushort* __restrict__ Wpk,  // packed weights
    void* __restrict__ Yv, int wbstride)
{
  const int b    = blockIdx.y;
  const int tile = blockIdx.x;
  const int ty0  = (tile / 6) * 12;
  const int tx0  = (tile % 6) * 16;
  const int tid  = threadIdx.x;
  const int lane = tid & 63;
  const int w8   = tid >> 6;         // 0..7
  const int wr   = w8 >> 1;          // row group 0..3
  const int half = w8 & 1;           // mt half
  const int nc   = lane & 15;
  const int q    = lane >> 4;

  __shared__ __attribute__((aligned(16))) ushort Xs[252 * 104];  // 52416 B

  // per-wave weight stream base: this wave's 3 mt fragments per chunk
  const ushort* wph = Wpk + (size_t)b * wbstride + (size_t)(half * 3) * 512
                    + lane * 8;

  // ---- stage X tile: 252 pixels x 96 ch from NHWC bf16, coalesced 16B
  const ushort* xb = Xn + (size_t)b * CHW;
  for (int it = 0; it < 6; ++it) {
    const int idx = it * 512 + tid;
    if (idx < 3024) {
      const int pix = (idx * 2731) >> 15;          // idx / 12
      const int c8  = idx - pix * 12;
      const int ly  = (pix * 57) >> 10;            // pix / 18
      const int lx  = pix - ly * 18;
      const int gy  = ty0 - 1 + ly, gx = tx0 - 1 + lx;
      short8 v = {0, 0, 0, 0, 0, 0, 0, 0};
      if (((unsigned)gy < 96u) & ((unsigned)gx < 96u))
        v = *(const short8*)(xb + ((size_t)gy * WW + gx) * 96 + c8 * 8);
      *(short8*)(&Xs[pix * 104 + c8 * 8]) = v;
    }
  }

  // preload chunk-0 weights while staging drains
  short8 af[3];
#pragma unroll
  for (int m = 0; m < 3; ++m)
    af[m] = *(const short8*)(wph + m * 512);

  floatx4 acc[3][3];
#pragma unroll
  for (int mtl = 0; mtl < 3; ++mtl)
#pragma unroll
    for (int t = 0; t < 3; ++t)
#pragma unroll
      for (int r = 0; r < 4; ++r) acc[mtl][t][r] = 0.f;

  __syncthreads();   // X tile resident; ONLY barrier in the kernel

  for (int ch = 0; ch < 27; ++ch) {   // NOT unrolled: small live window
    // prefetch next chunk's weights (no barrier anywhere to stall them)
    short8 afn[3];
    if (ch < 26) {
#pragma unroll
      for (int m = 0; m < 3; ++m)
        afn[m] = *(const short8*)(wph + (size_t)(ch + 1) * 3072 + m * 512);
    }

    const int o  = ch / 3;
    const int cc = ch - o * 3;
    const int dy = o / 3, dx = o - dy * 3;
    const int pc  = nc + dx;
    const int cib = cc * 32 + q * 8;

    short8 bfr[3];
#pragma unroll
    for (int t = 0; t < 3; ++t) {
      const int pix = (3 * wr + t + dy) * 18 + pc;
      bfr[t] = *(const short8*)(&Xs[pix * 104 + cib]);
    }

#pragma unroll
    for (int mtl = 0; mtl < 3; ++mtl)
#pragma unroll
      for (int t = 0; t < 3; ++t)
        acc[mtl][t] = __builtin_amdgcn_mfma_f32_16x16x32_bf16(
            af[mtl], bfr[t], acc[mtl][t], 0, 0, 0);

#pragma unroll
    for (int m = 0; m < 3; ++m) af[m] = afn[m];
  }

  // ---- epilogue
#pragma unroll
  for (int mtl = 0; mtl < 3; ++mtl)
#pragma unroll
    for (int t = 0; t < 3; ++t) {
      const int yy = ty0 + 3 * wr + t;
      const int xx = tx0 + nc;
#pragma unroll
      for (int r = 0; r < 4; ++r) {
        const int co = (half * 3 + mtl) * 16 + q * 4 + r;
        if constexpr (OUTM == 0) {
          // class-major: ty0 % 3 == 0 so kh = t, class-row = ty0/3 + wr
          const int cx = xx / 3;
          const int kw = xx - 3 * cx;
          const int kk = t * 3 + kw;
          const int cp = (ty0 / 3 + wr) * 32 + cx;
          ((uint*)Yv)[(((size_t)b * 9 + kk) * CH + co) * 1024 + cp] =
              packhl(acc[mtl][t][r]);
        } else if constexpr (OUTM == 1) {
          ((ushort*)Yv + (size_t)b * CHW)[((size_t)yy * WW + xx) * 96 + co] =
              f2bf(acc[mtl][t][r]);
        } else {
          ((float*)Yv + (size_t)b * CHW)[(size_t)co * HWI + yy * WW + xx] =
              acc[mtl][t][r];
        }
      }
    }
}

// ---------------------------------------------------------------------------
// Attention Gram GEMM, K-split x4 (unchanged). Y1/Y2 arrive CLASS-MAJOR
// [b][k][c][1024] hi/lo-packed -> coalesced uint4 staging.
// ---------------------------------------------------------------------------
__global__ __launch_bounds__(256) void attn_mfma(
    const uint* __restrict__ Y1, const uint* __restrict__ Y2,
    float* __restrict__ P0, float* __restrict__ P1,
    float* __restrict__ P2, float* __restrict__ P3)
{
  const int bi = blockIdx.x;
  const int b  = bi / 36;
  const int r9 = bi % 36;
  const int k  = r9 >> 2;
  const int qd = r9 & 3;
  const int tid  = threadIdx.x;
  const int lane = tid & 63;
  const int wv   = tid >> 6;          // 0..3

  __shared__ ushort Ah[96 * 72], Al[96 * 72], Bh[96 * 72], Bl[96 * 72];

  const uint* y1b = Y1 + ((size_t)(b * 9 + k) * CH) * 1024;
  const uint* y2b = Y2 + ((size_t)(b * 9 + k) * CH) * 1024;

  const int mg2 = wv >> 1;            // c half
  const int ng2 = wv & 1;             // d half
  const int cn = lane & 15;
  const int q  = lane >> 4;

  floatx4 acc[3][3];
#pragma unroll
  for (int i = 0; i < 3; ++i)
#pragma unroll
    for (int j = 0; j < 3; ++j)
#pragma unroll
      for (int r = 0; r < 4; ++r) acc[i][j][r] = 0.f;

  const int sj4  = tid & 15;          // pixel quad within slab (4 px each)
  const int sg16 = tid >> 4;          // 0..15: row group

  for (int ss = 0; ss < 4; ++ss) {
    const int s = qd * 4 + ss;        // slab: class pixels 64s..64s+63
    __syncthreads();
#pragma unroll
    for (int cg = 0; cg < 6; ++cg) {
      const int c = cg * 16 + sg16;
      const size_t goff = (size_t)c * 1024 + s * 64 + sj4 * 4;
      const uint4 u1 = *(const uint4*)(y1b + goff);
      const uint4 u2 = *(const uint4*)(y2b + goff);
      const int lbase = c * 72 + sj4 * 4;           // 8B-aligned (144c+8sj4)
      uint2 w;
      // A hi
      w.x = (u1.x & 0xffffu) | (u1.y << 16);
      w.y = (u1.z & 0xffffu) | (u1.w << 16);
      *(uint2*)(&Ah[lbase]) = w;
      // A lo
      w.x = (u1.x >> 16) | (u1.y & 0xffff0000u);
      w.y = (u1.z >> 16) | (u1.w & 0xffff0000u);
      *(uint2*)(&Al[lbase]) = w;
      // B hi
      w.x = (u2.x & 0xffffu) | (u2.y << 16);
      w.y = (u2.z & 0xffffu) | (u2.w << 16);
      *(uint2*)(&Bh[lbase]) = w;
      // B lo
      w.x = (u2.x >> 16) | (u2.y & 0xffff0000u);
      w.y = (u2.z >> 16) | (u2.w & 0xffff0000u);
      *(uint2*)(&Bl[lbase]) = w;
    }
    __syncthreads();

#pragma unroll
    for (int kc = 0; kc < 2; ++kc) {
      short8 ah[3], al[3], bh[3], bl[3];
#pragma unroll
      for (int t = 0; t < 3; ++t) {
        const int offA = (mg2 * 48 + t * 16 + cn) * 72 + kc * 32 + q * 8;
        ah[t] = *(const short8*)(&Ah[offA]);
        al[t] = *(const short8*)(&Al[offA]);
        const int offB = (ng2 * 48 + t * 16 + cn) * 72 + kc * 32 + q * 8;
        bh[t] = *(const short8*)(&Bh[offB]);
        bl[t] = *(const short8*)(&Bl[offB]);
      }
#pragma unroll
      for (int i = 0; i < 3; ++i)
#pragma unroll
        for (int j = 0; j < 3; ++j) {
          acc[i][j] = __builtin_amdgcn_mfma_f32_16x16x32_bf16(
              ah[i], bh[j], acc[i][j], 0, 0, 0);
          acc[i][j] = __builtin_amdgcn_mfma_f32_16x16x32_bf16(
              ah[i], bl[j], acc[i][j], 0, 0, 0);
          acc[i][j] = __builtin_amdgcn_mfma_f32_16x16x32_bf16(
              al[i], bh[j], acc[i][j], 0, 0, 0);
        }
    }
  }

  float* P = (qd == 0) ? P0 : (qd == 1) ? P1 : (qd == 2) ? P2 : P3;
#pragma unroll
  for (int i = 0; i < 3; ++i)
#pragma unroll
    for (int j = 0; j < 3; ++j)
#pragma unroll
      for (int r = 0; r < 4; ++r) {
        const int c = mg2 * 48 + i * 16 + q * 4 + r;
        const int d = ng2 * 48 + j * 16 + cn;
        P[((size_t)(b * CH + d) * CH + c) * 9 + k] = acc[i][j][r];
      }
}

// ---------------------------------------------------------------------------
// Softmax over m = c*9+k (864 values) per (b,d) row; folds 4 K-partials.
// (unchanged; dst aliases P1 safely)
// ---------------------------------------------------------------------------
__global__ __launch_bounds__(256) void softmax_k(
    const float* __restrict__ P0, const float* __restrict__ P1,
    const float* __restrict__ P2, const float* __restrict__ P3,
    float* __restrict__ attnW)
{
  const int bd = blockIdx.x;
  const size_t base = (size_t)bd * 864;
  float* dst = attnW + base;
  const float rs = 0.0340216824f;          // 1/sqrt(864)
  const int tid = threadIdx.x;

  const size_t i0 = base + tid;
  float v0 = P0[i0] + P1[i0] + P2[i0] + P3[i0];
  float v1 = P0[i0 + 256] + P1[i0 + 256] + P2[i0 + 256] + P3[i0 + 256];
  float v2 = P0[i0 + 512] + P1[i0 + 512] + P2[i0 + 512] + P3[i0 + 512];
  float v3 = (tid < 96)
      ? (P0[i0 + 768] + P1[i0 + 768] + P2[i0 + 768] + P3[i0 + 768])
      : -3.0e38f;

  float mx = fmaxf(fmaxf(v0, v1), fmaxf(v2, v3));

  __shared__ float red[256];
  red[tid] = mx;
  __syncthreads();
#pragma unroll
  for (int s = 128; s > 0; s >>= 1) {
    if (tid < s) red[tid] = fmaxf(red[tid], red[tid + s]);
    __syncthreads();
  }
  mx = red[0];
  __syncthreads();

  const float e0 = expf((v0 - mx) * rs);
  const float e1 = expf((v1 - mx) * rs);
  const float e2 = expf((v2 - mx) * rs);
  const float e3 = (tid < 96) ? expf((v3 - mx) * rs) : 0.f;

  red[tid] = e0 + e1 + e2 + e3;
  __syncthreads();
#pragma unroll
  for (int s = 128; s > 0; s >>= 1) {
    if (tid < s) red[tid] += red[tid + s];
    __syncthreads();
  }
  const float inv = 1.f / red[0];

  dst[tid]       = e0 * inv;
  dst[tid + 256] = e1 * inv;
  dst[tid + 512] = e2 * inv;
  if (tid < 96) dst[tid + 768] = e3 * inv;
}

// ---------------------------------------------------------------------------
extern "C" void kernel_launch(void* const* d_in, const int* in_sizes, int n_in,
                              void* d_out, int out_size, void* d_ws, size_t ws_size,
                              hipStream_t stream)
{
  const float* x  = (const float*)d_in[0];
  const float* W1 = (const float*)d_in[1];
  const float* W2 = (const float*)d_in[2];
  const float* W3 = (const float*)d_in[3];

  float* ws    = (float*)d_ws;
  uint*  Y1    = (uint*)ws;                 // IMG uints (hi/lo, class-major)
  uint*  Y2    = Y1 + (size_t)IMG;          // IMG uints
  float* attnT = (float*)(Y2 + (size_t)IMG);// ATT floats (partial 0)
  float* attnW = attnT + ATT;               // ATT floats (partial 1 -> weights)
  ushort* pk   = (ushort*)(attnW + ATT);
  ushort* pkW1 = pk;
  ushort* pkW2 = pk + WPK;
  ushort* pkW3 = pk + 2 * (size_t)WPK;
  ushort* pkAW = pk + 3 * (size_t)WPK;      // 16 batch matrices
  ushort* Xn   = pkAW + 16 * (size_t)WPK;   // IMG ushorts (x bf16 NHWC)
  float* Pd2   = (float*)d_out;             // partials 2,3 in dead d_out
  float* Pd3   = Pd2 + ATT;
  ushort* Y3n  = (ushort*)Y1;               // Y1 region dead after attn

  const dim3 cgrid(48, BB);                 // 8x6 spatial tiles x batch

  xcast    <<<dim3(36, BB), 256, 0, stream>>>(x, Xn);

  prepack  <<<dim3(324, 1),  256, 0, stream>>>(W1, pkW1);
  prepack  <<<dim3(324, 1),  256, 0, stream>>>(W2, pkW2);
  prepack  <<<dim3(324, 1),  256, 0, stream>>>(W3, pkW3);

  conv_nb<0><<<cgrid, 512, 0, stream>>>(Xn, pkW1, Y1, 0);
  conv_nb<0><<<cgrid, 512, 0, stream>>>(Xn, pkW2, Y2, 0);

  attn_mfma<<<BB * 9 * 4, 256, 0, stream>>>(Y1, Y2, attnT, attnW, Pd2, Pd3);
  softmax_k<<<BB * CH, 256, 0, stream>>>(attnT, attnW, Pd2, Pd3, attnW);

  prepack  <<<dim3(324, BB), 256, 0, stream>>>(attnW, pkAW);

  conv_nb<1><<<cgrid, 512, 0, stream>>>(Xn, pkW3, Y3n, 0);
  conv_nb<2><<<cgrid, 512, 0, stream>>>(Y3n, pkAW, d_out, WPK);
}